// Round 1
// baseline (17990.413 us; speedup 1.0000x reference)
//
#include <hip/hip_runtime.h>
#include <cstddef>

#define DEV static __device__ __forceinline__

constexpr int B_TOTAL = 32768;
constexpr int ROWS_PER_BLOCK = 64;
constexpr int P_BLOCKS = B_TOTAL / ROWS_PER_BLOCK;  // 512
constexpr int Q_BLOCKS = B_TOTAL / ROWS_PER_BLOCK;  // 512

DEV float fexp2(float x) { return __builtin_amdgcn_exp2f(x); }
DEV float frcp(float x) { return __builtin_amdgcn_rcpf(x); }
// sigmoid(x) = 1/(1+2^(-x*log2e))
DEV float fsigmoid(float x) { return frcp(1.0f + fexp2(-1.4426950408889634f * x)); }
// tanh(x) = 2*sigmoid(2x)-1 ; safe at both extremes (rcp(inf)=0)
DEV float ftanh_(float x) { return 2.0f * frcp(1.0f + fexp2(-2.8853900817779268f * x)) - 1.0f; }

// One LSTM cell step. Gate order (torch): i, f, g, o along the 4H axis.
// Wih: [4H, DIN] row-major, Whh: [4H, H], bias: [4H] (b_ih+b_hh combined).
template <int DIN, int H>
DEV void lstm_step(const float* __restrict__ Wih, const float* __restrict__ Whh,
                   const float* __restrict__ bias,
                   const float (&x)[DIN], float (&h)[H], float (&c)[H]) {
  float hn[H];
#pragma unroll
  for (int k = 0; k < H; ++k) {
    float gi = bias[0 * H + k];
    float gf = bias[1 * H + k];
    float gg = bias[2 * H + k];
    float go = bias[3 * H + k];
#pragma unroll
    for (int j = 0; j < DIN; ++j) {
      const float xj = x[j];
      gi = fmaf(Wih[(0 * H + k) * DIN + j], xj, gi);
      gf = fmaf(Wih[(1 * H + k) * DIN + j], xj, gf);
      gg = fmaf(Wih[(2 * H + k) * DIN + j], xj, gg);
      go = fmaf(Wih[(3 * H + k) * DIN + j], xj, go);
    }
#pragma unroll
    for (int j = 0; j < H; ++j) {
      const float hj = h[j];
      gi = fmaf(Whh[(0 * H + k) * H + j], hj, gi);
      gf = fmaf(Whh[(1 * H + k) * H + j], hj, gf);
      gg = fmaf(Whh[(2 * H + k) * H + j], hj, gg);
      go = fmaf(Whh[(3 * H + k) * H + j], hj, go);
    }
    const float cn = fsigmoid(gf) * c[k] + fsigmoid(gi) * ftanh_(gg);
    c[k] = cn;
    hn[k] = fsigmoid(go) * ftanh_(cn);
  }
#pragma unroll
  for (int k = 0; k < H; ++k) h[k] = hn[k];
}

// blocks [0, P_BLOCKS)          -> p tower (T=50), long pole first
// blocks [P_BLOCKS, +Q_BLOCKS)  -> q tower (T=12)
__global__ __launch_bounds__(ROWS_PER_BLOCK, 1) void lstm_towers(
    const float* __restrict__ q, const float* __restrict__ p,
    const float* __restrict__ qWih0, const float* __restrict__ qWhh0, const float* __restrict__ qb0,
    const float* __restrict__ qWih1, const float* __restrict__ qWhh1, const float* __restrict__ qb1,
    const float* __restrict__ qWih2, const float* __restrict__ qWhh2, const float* __restrict__ qb2,
    const float* __restrict__ pWih0, const float* __restrict__ pWhh0, const float* __restrict__ pb0,
    const float* __restrict__ pWih1, const float* __restrict__ pWhh1, const float* __restrict__ pb1,
    const float* __restrict__ pWih2, const float* __restrict__ pWhh2, const float* __restrict__ pb2,
    float* __restrict__ hq, float* __restrict__ hp) {
  const int bid = blockIdx.x;
  const bool is_p = bid < P_BLOCKS;
  const int row = (is_p ? bid : bid - P_BLOCKS) * ROWS_PER_BLOCK + (int)threadIdx.x;
  const int T = is_p ? 50 : 12;

  const float* __restrict__ x = is_p ? p : q;
  const float* __restrict__ Wih0 = is_p ? pWih0 : qWih0;
  const float* __restrict__ Whh0 = is_p ? pWhh0 : qWhh0;
  const float* __restrict__ b0 = is_p ? pb0 : qb0;
  const float* __restrict__ Wih1 = is_p ? pWih1 : qWih1;
  const float* __restrict__ Whh1 = is_p ? pWhh1 : qWhh1;
  const float* __restrict__ b1 = is_p ? pb1 : qb1;
  const float* __restrict__ Wih2 = is_p ? pWih2 : qWih2;
  const float* __restrict__ Whh2 = is_p ? pWhh2 : qWhh2;
  const float* __restrict__ b2 = is_p ? pb2 : qb2;
  float* __restrict__ hout = is_p ? hp : hq;

  float h0[25], c0[25], h1[10], c1[10], h2[4], c2[4];
#pragma unroll
  for (int k = 0; k < 25; ++k) { h0[k] = 0.0f; c0[k] = 0.0f; }
#pragma unroll
  for (int k = 0; k < 10; ++k) { h1[k] = 0.0f; c1[k] = 0.0f; }
#pragma unroll
  for (int k = 0; k < 4; ++k) { h2[k] = 0.0f; c2[k] = 0.0f; }

  const float* xrow = x + (size_t)row * (size_t)T * 50;
  for (int t = 0; t < T; ++t) {
    float xt[50];
    // row start is 8B-aligned (200B per timestep row) -> float2 loads
    const float2* xp2 = reinterpret_cast<const float2*>(xrow + t * 50);
#pragma unroll
    for (int j = 0; j < 25; ++j) {
      const float2 v = xp2[j];
      xt[2 * j + 0] = v.x;
      xt[2 * j + 1] = v.y;
    }
    lstm_step<50, 25>(Wih0, Whh0, b0, xt, h0, c0);
    lstm_step<25, 10>(Wih1, Whh1, b1, h0, h1, c1);
    lstm_step<10, 4>(Wih2, Whh2, b2, h1, h2, c2);
  }

  reinterpret_cast<float4*>(hout)[row] = make_float4(h2[0], h2[1], h2[2], h2[3]);
}

__global__ __launch_bounds__(256) void combine_head(
    const float* __restrict__ hq, const float* __restrict__ hp,
    const float* __restrict__ fW, const float* __restrict__ fb,
    float* __restrict__ out) {
  const int b = blockIdx.x * blockDim.x + (int)threadIdx.x;
  if (b >= B_TOTAL) return;
  const float4 vq = reinterpret_cast<const float4*>(hq)[b];
  const float4 vp = reinterpret_cast<const float4*>(hp)[b];
  const float s0 = vq.x * vp.x, s1 = vq.y * vp.y, s2 = vq.z * vp.z, s3 = vq.w * vp.w;
  float l0 = fb[0];
  float l1 = fb[1];
  l0 = fmaf(s0, fW[0], l0); l0 = fmaf(s1, fW[1], l0); l0 = fmaf(s2, fW[2], l0); l0 = fmaf(s3, fW[3], l0);
  l1 = fmaf(s0, fW[4], l1); l1 = fmaf(s1, fW[5], l1); l1 = fmaf(s2, fW[6], l1); l1 = fmaf(s3, fW[7], l1);
  const float m = fmaxf(l0, l1);
  const float e0 = fexp2(1.4426950408889634f * (l0 - m));
  const float e1 = fexp2(1.4426950408889634f * (l1 - m));
  const float inv = frcp(e0 + e1);
  reinterpret_cast<float2*>(out)[b] = make_float2(e0 * inv, e1 * inv);
}

extern "C" void kernel_launch(void* const* d_in, const int* in_sizes, int n_in,
                              void* d_out, int out_size, void* d_ws, size_t ws_size,
                              hipStream_t stream) {
  const float* q = (const float*)d_in[0];
  const float* p = (const float*)d_in[1];
  const float* qWih0 = (const float*)d_in[2];
  const float* qWhh0 = (const float*)d_in[3];
  const float* qb0 = (const float*)d_in[4];
  const float* qWih1 = (const float*)d_in[5];
  const float* qWhh1 = (const float*)d_in[6];
  const float* qb1 = (const float*)d_in[7];
  const float* qWih2 = (const float*)d_in[8];
  const float* qWhh2 = (const float*)d_in[9];
  const float* qb2 = (const float*)d_in[10];
  const float* pWih0 = (const float*)d_in[11];
  const float* pWhh0 = (const float*)d_in[12];
  const float* pb0 = (const float*)d_in[13];
  const float* pWih1 = (const float*)d_in[14];
  const float* pWhh1 = (const float*)d_in[15];
  const float* pb1 = (const float*)d_in[16];
  const float* pWih2 = (const float*)d_in[17];
  const float* pWhh2 = (const float*)d_in[18];
  const float* pb2 = (const float*)d_in[19];
  const float* fW = (const float*)d_in[20];
  const float* fb = (const float*)d_in[21];

  float* hq = (float*)d_ws;                 // [B,4]
  float* hp = hq + (size_t)B_TOTAL * 4;     // [B,4]  (1 MB total in d_ws)
  float* out = (float*)d_out;               // [B,2]

  lstm_towers<<<P_BLOCKS + Q_BLOCKS, ROWS_PER_BLOCK, 0, stream>>>(
      q, p,
      qWih0, qWhh0, qb0, qWih1, qWhh1, qb1, qWih2, qWhh2, qb2,
      pWih0, pWhh0, pb0, pWih1, pWhh1, pb1, pWih2, pWhh2, pb2,
      hq, hp);

  combine_head<<<B_TOTAL / 256, 256, 0, stream>>>(hq, hp, fW, fb, out);
}

// Round 2
// 3194.589 us; speedup vs baseline: 5.6315x; 5.6315x over previous
//
#include <hip/hip_runtime.h>
#include <cstddef>

#define DEV static __device__ __forceinline__

constexpr int B_TOTAL = 32768;
constexpr int ROWS = 64;              // batch rows per block
constexpr int PB = B_TOTAL / ROWS;    // 512 p blocks
constexpr int QB = B_TOTAL / ROWS;    // 512 q blocks

// Transposed-weight layout per tower (floats):
//   TW0[75][100] @0, TW1[35][40] @7500, TW2[14][16] @8900,
//   b0'[100] @9124, b1'[40] @9224, b2'[16] @9264  -> total 9280
// k' index = unit*4 + gate_type  (gate_type: 0=i,1=f,2=g,3=o) so each unit's
// 4 gate weights for a given j are ONE aligned float4.
constexpr int TW1_OFF = 7500, TW2_OFF = 8900;
constexpr int BP0_OFF = 9124, BP1_OFF = 9224, BP2_OFF = 9264;
constexpr int TOW_FLOATS = 9280;
constexpr int HQ_OFF = 2 * TOW_FLOATS;           // 18560
constexpr int HP_OFF = HQ_OFF + B_TOTAL * 4;     // +131072

DEV float fexp2(float x) { return __builtin_amdgcn_exp2f(x); }
DEV float frcp(float x) { return __builtin_amdgcn_rcpf(x); }
DEV float fsig(float x) { return frcp(1.0f + fexp2(-1.4426950408889634f * x)); }
DEV float ftanh_(float x) { return 2.0f * frcp(1.0f + fexp2(-2.8853900817779268f * x)) - 1.0f; }

// ---------------- prep: transpose + gate-interleave weights into ws ----------
__global__ __launch_bounds__(256) void prep_weights(
    const float* __restrict__ qWih0, const float* __restrict__ qWhh0, const float* __restrict__ qb0,
    const float* __restrict__ qWih1, const float* __restrict__ qWhh1, const float* __restrict__ qb1,
    const float* __restrict__ qWih2, const float* __restrict__ qWhh2, const float* __restrict__ qb2,
    const float* __restrict__ pWih0, const float* __restrict__ pWhh0, const float* __restrict__ pb0,
    const float* __restrict__ pWih1, const float* __restrict__ pWhh1, const float* __restrict__ pb1,
    const float* __restrict__ pWih2, const float* __restrict__ pWhh2, const float* __restrict__ pb2,
    float* __restrict__ ws) {
  const bool isp = (blockIdx.x == 1);
  const float* Wih0 = isp ? pWih0 : qWih0; const float* Whh0 = isp ? pWhh0 : qWhh0;
  const float* b0   = isp ? pb0   : qb0;
  const float* Wih1 = isp ? pWih1 : qWih1; const float* Whh1 = isp ? pWhh1 : qWhh1;
  const float* b1   = isp ? pb1   : qb1;
  const float* Wih2 = isp ? pWih2 : qWih2; const float* Whh2 = isp ? pWhh2 : qWhh2;
  const float* b2   = isp ? pb2   : qb2;
  float* out = ws + (isp ? TOW_FLOATS : 0);

  for (int e = threadIdx.x; e < TOW_FLOATS; e += 256) {
    float v;
    if (e < TW1_OFF) {            // layer0: K=75 (50+25), N=100
      const int i = e, j = i / 100, k = i % 100, u = k >> 2, gt = k & 3;
      const int rr = gt * 25 + u;
      v = (j < 50) ? Wih0[rr * 50 + j] : Whh0[rr * 25 + (j - 50)];
    } else if (e < TW2_OFF) {     // layer1: K=35 (25+10), N=40
      const int i = e - TW1_OFF, j = i / 40, k = i % 40, u = k >> 2, gt = k & 3;
      const int rr = gt * 10 + u;
      v = (j < 25) ? Wih1[rr * 25 + j] : Whh1[rr * 10 + (j - 25)];
    } else if (e < BP0_OFF) {     // layer2: K=14 (10+4), N=16
      const int i = e - TW2_OFF, j = i / 16, k = i % 16, u = k >> 2, gt = k & 3;
      const int rr = gt * 4 + u;
      v = (j < 10) ? Wih2[rr * 10 + j] : Whh2[rr * 4 + (j - 10)];
    } else if (e < BP1_OFF) {
      const int k = e - BP0_OFF, u = k >> 2, gt = k & 3; v = b0[gt * 25 + u];
    } else if (e < BP2_OFF) {
      const int k = e - BP1_OFF, u = k >> 2, gt = k & 3; v = b1[gt * 10 + u];
    } else {
      const int k = e - BP2_OFF, u = k >> 2, gt = k & 3; v = b2[gt * 4 + u];
    }
    out[e] = v;
  }
}

// --------------- one LSTM layer timestep for NU units of this wave -----------
// tw: transposed weights [K][4H] (k' interleaved), bp: permuted bias [4H]
// xin/hin: LDS input and self-h buffers, lane r = its batch row.
template <int DIN, int H, int NU>
DEV void layer_step(const float* __restrict__ tw, const float* __restrict__ bp,
                    const float* xin, const int xstr,
                    const float* hin, const int hstr,
                    const int u0, float* c, float* hout, const int r) {
  float g[4 * NU];
#pragma unroll
  for (int k = 0; k < 4 * NU; ++k) g[k] = bp[4 * u0 + k];

  for (int j = 0; j < DIN; ++j) {
    const float v = xin[r * xstr + j];
    const float4* __restrict__ w = reinterpret_cast<const float4*>(tw + j * 4 * H) + u0;
#pragma unroll
    for (int u = 0; u < NU; ++u) {
      const float4 wv = w[u];
      g[4 * u + 0] = fmaf(wv.x, v, g[4 * u + 0]);
      g[4 * u + 1] = fmaf(wv.y, v, g[4 * u + 1]);
      g[4 * u + 2] = fmaf(wv.z, v, g[4 * u + 2]);
      g[4 * u + 3] = fmaf(wv.w, v, g[4 * u + 3]);
    }
  }
  for (int j = 0; j < H; ++j) {
    const float v = hin[r * hstr + j];
    const float4* __restrict__ w = reinterpret_cast<const float4*>(tw + (DIN + j) * 4 * H) + u0;
#pragma unroll
    for (int u = 0; u < NU; ++u) {
      const float4 wv = w[u];
      g[4 * u + 0] = fmaf(wv.x, v, g[4 * u + 0]);
      g[4 * u + 1] = fmaf(wv.y, v, g[4 * u + 1]);
      g[4 * u + 2] = fmaf(wv.z, v, g[4 * u + 2]);
      g[4 * u + 3] = fmaf(wv.w, v, g[4 * u + 3]);
    }
  }
#pragma unroll
  for (int u = 0; u < NU; ++u) {
    const float gi = fsig(g[4 * u + 0]);
    const float gf = fsig(g[4 * u + 1]);
    const float gg = ftanh_(g[4 * u + 2]);
    const float go = fsig(g[4 * u + 3]);
    const float cn = fmaf(gf, c[u], gi * gg);
    c[u] = cn;
    hout[u] = go * ftanh_(cn);
  }
}

// blocks [0,PB) -> p tower (T=50, the long pole); [PB, PB+QB) -> q tower (T=12)
// 128 threads = 2 waves; wave 0 takes units [0,13)/[0,5)/[0,2), wave 1 the rest.
__global__ __launch_bounds__(128) void lstm_towers(const float* __restrict__ q,
                                                   const float* __restrict__ p,
                                                   float* __restrict__ ws) {
  __shared__ float xb[64 * 51];   // x_t, stride 51 (odd -> conflict-free)
  __shared__ float h0b[64 * 25];  // stride 25 (odd)
  __shared__ float h1b[64 * 11];  // stride 11 (odd)
  __shared__ float h2b[64 * 5];   // stride 5 (odd)

  const int bid = blockIdx.x;
  const bool isp = bid < PB;
  const int row0 = (isp ? bid : bid - PB) * ROWS;
  const int T = isp ? 50 : 12;
  const float* __restrict__ x = isp ? p : q;
  const float* __restrict__ tw = ws + (isp ? TOW_FLOATS : 0);
  float* __restrict__ hout_g = ws + (isp ? HP_OFF : HQ_OFF);

  const int tid = threadIdx.x;
  const int r = tid & 63;
  const int wid = tid >> 6;
  const int u00 = wid ? 13 : 0;
  const int u01 = wid ? 5 : 0;
  const int u02 = wid ? 2 : 0;

  const float* tw0 = tw;            const float* bp0 = tw + BP0_OFF;
  const float* tw1 = tw + TW1_OFF;  const float* bp1 = tw + BP1_OFF;
  const float* tw2 = tw + TW2_OFF;  const float* bp2 = tw + BP2_OFF;

  // zero initial hidden state (visible after the first post-x-load barrier)
  for (int i = tid; i < 64 * 25; i += 128) h0b[i] = 0.0f;
  for (int i = tid; i < 64 * 11; i += 128) h1b[i] = 0.0f;
  for (int i = tid; i < 64 * 5; i += 128) h2b[i] = 0.0f;

  float c0[13] = {}, c1[5] = {}, c2[2] = {};
  float h0n[13], h1n[5], h2n[2];

  for (int t = 0; t < T; ++t) {
    // cooperative x_t load: 64 rows x 50 floats (as 1600 float2)
    for (int i = tid; i < 1600; i += 128) {
      const int rr = i / 25, j2 = i % 25;
      const float2 v = *reinterpret_cast<const float2*>(
          x + ((size_t)(row0 + rr) * T + t) * 50 + 2 * j2);
      xb[rr * 51 + 2 * j2] = v.x;
      xb[rr * 51 + 2 * j2 + 1] = v.y;
    }
    __syncthreads();  // x_t ready; h*_{t-1} (and zero-init) visible
    if (wid == 0) layer_step<50, 25, 13>(tw0, bp0, xb, 51, h0b, 25, 0,  c0, h0n, r);
    else          layer_step<50, 25, 12>(tw0, bp0, xb, 51, h0b, 25, 13, c0, h0n, r);
    __syncthreads();  // all reads of h0_{t-1} done
    {
      const int nu = wid ? 12 : 13;
      for (int u = 0; u < nu; ++u) h0b[r * 25 + u00 + u] = h0n[u];
    }
    __syncthreads();  // h0_t visible
    layer_step<25, 10, 5>(tw1, bp1, h0b, 25, h1b, 11, u01, c1, h1n, r);
    __syncthreads();
    for (int u = 0; u < 5; ++u) h1b[r * 11 + u01 + u] = h1n[u];
    __syncthreads();
    layer_step<10, 4, 2>(tw2, bp2, h1b, 11, h2b, 5, u02, c2, h2n, r);
    __syncthreads();
    h2b[r * 5 + u02 + 0] = h2n[0];
    h2b[r * 5 + u02 + 1] = h2n[1];
    __syncthreads();  // h2_t visible before next step / output
  }

  if (tid < 64) {
    const float4 o = make_float4(h2b[r * 5 + 0], h2b[r * 5 + 1],
                                 h2b[r * 5 + 2], h2b[r * 5 + 3]);
    reinterpret_cast<float4*>(hout_g)[row0 + r] = o;
  }
}

// ---------------- head: softmax((hq*hp) @ fW^T + fb) -------------------------
__global__ __launch_bounds__(256) void combine_head(
    const float* __restrict__ hq, const float* __restrict__ hp,
    const float* __restrict__ fW, const float* __restrict__ fb,
    float* __restrict__ out) {
  const int b = blockIdx.x * blockDim.x + (int)threadIdx.x;
  if (b >= B_TOTAL) return;
  const float4 vq = reinterpret_cast<const float4*>(hq)[b];
  const float4 vp = reinterpret_cast<const float4*>(hp)[b];
  const float s0 = vq.x * vp.x, s1 = vq.y * vp.y, s2 = vq.z * vp.z, s3 = vq.w * vp.w;
  float l0 = fb[0], l1 = fb[1];
  l0 = fmaf(s0, fW[0], l0); l0 = fmaf(s1, fW[1], l0); l0 = fmaf(s2, fW[2], l0); l0 = fmaf(s3, fW[3], l0);
  l1 = fmaf(s0, fW[4], l1); l1 = fmaf(s1, fW[5], l1); l1 = fmaf(s2, fW[6], l1); l1 = fmaf(s3, fW[7], l1);
  const float m = fmaxf(l0, l1);
  const float e0 = fexp2(1.4426950408889634f * (l0 - m));
  const float e1 = fexp2(1.4426950408889634f * (l1 - m));
  const float inv = frcp(e0 + e1);
  reinterpret_cast<float2*>(out)[b] = make_float2(e0 * inv, e1 * inv);
}

extern "C" void kernel_launch(void* const* d_in, const int* in_sizes, int n_in,
                              void* d_out, int out_size, void* d_ws, size_t ws_size,
                              hipStream_t stream) {
  const float* q = (const float*)d_in[0];
  const float* p = (const float*)d_in[1];
  float* ws = (float*)d_ws;

  prep_weights<<<2, 256, 0, stream>>>(
      (const float*)d_in[2], (const float*)d_in[3], (const float*)d_in[4],
      (const float*)d_in[5], (const float*)d_in[6], (const float*)d_in[7],
      (const float*)d_in[8], (const float*)d_in[9], (const float*)d_in[10],
      (const float*)d_in[11], (const float*)d_in[12], (const float*)d_in[13],
      (const float*)d_in[14], (const float*)d_in[15], (const float*)d_in[16],
      (const float*)d_in[17], (const float*)d_in[18], (const float*)d_in[19],
      ws);

  lstm_towers<<<PB + QB, 128, 0, stream>>>(q, p, ws);

  combine_head<<<B_TOTAL / 256, 256, 0, stream>>>(
      ws + HQ_OFF, ws + HP_OFF,
      (const float*)d_in[20], (const float*)d_in[21], (float*)d_out);
}